// Round 4
// baseline (114.629 us; speedup 1.0000x reference)
//
#include <hip/hip_runtime.h>

#define HW (512 * 512)

typedef float vfloat4 __attribute__((ext_vector_type(4)));  // clang-native: OK for nontemporal builtins

constexpr float BWIDTH = 1.0f / 15.0f;
constexpr float DELTA = 3e-5f;        // guard >= ~2.5x the 1.2e-5 fast-path error bound

// Barrier-free rolling-row kernel: one wave owns 4 full 512-px rows (8 px/lane as
// two coalesced 4-px half-rows at cols 4L and 256+4L). Rows load once, argmax-nib
// reused as bottom->mid->top. Neighbor counts via packed-nibble SWAR in registers
// (nib16 = 1<<(4*cls) per px, 2 px/word): colsum T+M+B <= 3/nibble, 3x3 sum <= 9,
// minus center >= 0 -> carry/borrow-free. No __syncthreads anywhere.
__global__ __launch_bounds__(256) void nectar_binning_kernel(
    const float* __restrict__ logits,      // [16,4,512,512]
    const float* __restrict__ val_freqs,   // [4,9,15]
    float* __restrict__ out)               // [16,4,512,512]
{
    __shared__ float vf[540];

    const int tid  = (int)threadIdx.x;
    const int lane = tid & 63;
    const int wv   = tid >> 6;

    // vf: per-wave redundant preload (identical values from all waves -> benign
    // race; each wave reads only after its own ds_writes, ordered by lgkmcnt).
    // Issued FIRST so the later ds_write's vmcnt wait does not drain row loads.
    float vfr[9];
    #pragma unroll
    for (int i = 0; i < 9; i++) {
        int idx = 64 * i + lane;
        vfr[i] = (idx < 540) ? val_freqs[idx] : 0.f;
    }

    // segment map: 2048 segments of 4 rows; waves of a block take ADJACENT
    // segments (boundary rows shared via L1/L2); XCD-chunk block swizzle
    // (bijective, 512 % 8 == 0) keeps neighboring segments on one XCD L2.
    const unsigned bi  = blockIdx.x;
    const unsigned bsw = ((bi & 7u) << 6) | (bi >> 3);
    const int seg = (int)(4u * bsw) + wv;   // 0..2047
    const int b   = seg >> 7;               // batch
    const int grp = seg & 127;              // row-group within image
    const int h0  = grp << 2;

    const float* lb = logits + (size_t)b * 4 * HW;
    float*       ob = out    + (size_t)b * 4 * HW;
    const int colA = 4 * lane;
    const int colB = 256 + 4 * lane;

    auto LOADROW = [&](vfloat4 (&dst)[4][2], int r) {
        const float* rp = lb + (r << 9);
        #pragma unroll
        for (int c = 0; c < 4; c++) {
            dst[c][0] = *reinterpret_cast<const vfloat4*>(rp + (size_t)c * HW + colA);
            dst[c][1] = *reinterpret_cast<const vfloat4*>(rp + (size_t)c * HW + colB);
        }
    };

    // argmax -> nib16 only (halo rows). First-index tie-break, verbatim since R2.
    auto NIBROW = [&](const vfloat4 (&x)[4][2], unsigned (&N)[2][2]) {
        #pragma unroll
        for (int h = 0; h < 2; h++) {
            unsigned n[4];
            #pragma unroll
            for (int j = 0; j < 4; j++) {
                float x0 = x[0][h][j], x1 = x[1][h][j], x2 = x[2][h][j], x3 = x[3][h][j];
                int c = 0; float best = x0;
                if (x1 > best) { best = x1; c = 1; }
                if (x2 > best) { best = x2; c = 2; }
                if (x3 > best) { best = x3; c = 3; }
                n[j] = 1u << (4 * c);
            }
            N[h][0] = n[0] | (n[1] << 16);
            N[h][1] = n[2] | (n[3] << 16);
        }
    };

    // argmax + softmax->bins (interior rows). Numeric path verbatim from R0-R3.
    auto NIBPBROW = [&](const vfloat4 (&x)[4][2], unsigned (&N)[2][2], unsigned (&P)[2][2]) {
        #pragma unroll
        for (int h = 0; h < 2; h++) {
            unsigned n[4], pbv[4];
            #pragma unroll
            for (int j = 0; j < 4; j++) {
                float x0 = x[0][h][j], x1 = x[1][h][j], x2 = x[2][h][j], x3 = x[3][h][j];
                int c = 0; float best = x0;
                if (x1 > best) { best = x1; c = 1; }
                if (x2 > best) { best = x2; c = 2; }
                if (x3 > best) { best = x3; c = 3; }
                n[j] = 1u << (4 * c);

                float m = fmaxf(fmaxf(x0, x1), fmaxf(x2, x3));
                float t0 = x0 - m, t1 = x1 - m, t2 = x2 - m, t3 = x3 - m;
                // fast path: native exp + rcp; |q_fast - q_exact| <= ~1.2e-5 << DELTA
                float f0 = __expf(t0), f1 = __expf(t1), f2 = __expf(t2), f3 = __expf(t3);
                float sf = ((f0 + f1) + f2) + f3;
                float rs = __builtin_amdgcn_rcpf(sf);
                float q[4];
                q[0] = (f0 * rs) * 15.0f; q[1] = (f1 * rs) * 15.0f;
                q[2] = (f2 * rs) * 15.0f; q[3] = (f3 * rs) * 15.0f;
                bool slow = false;
                #pragma unroll
                for (int c2 = 0; c2 < 4; c2++) {
                    float fr = q[c2] - floorf(q[c2]);
                    slow |= (fr < DELTA) | (fr > 1.0f - DELTA);
                }
                if (slow) {  // exact ocml-exp + IEEE-divide chain (matches np)
                    float e0 = expf(t0), e1 = expf(t1), e2 = expf(t2), e3 = expf(t3);
                    float s = ((e0 + e1) + e2) + e3;
                    q[0] = (e0 / s) / BWIDTH; q[1] = (e1 / s) / BWIDTH;
                    q[2] = (e2 / s) / BWIDTH; q[3] = (e3 / s) / BWIDTH;
                }
                unsigned pb = 0;
                #pragma unroll
                for (int c2 = 0; c2 < 4; c2++) {
                    int bin = (int)q[c2];
                    bin = bin > 14 ? 14 : bin;
                    pb |= (unsigned)bin << (4 * c2);
                }
                pbv[j] = pb;
            }
            N[h][0] = n[0]   | (n[1]   << 16);
            N[h][1] = n[2]   | (n[3]   << 16);
            P[h][0] = pbv[0] | (pbv[1] << 16);
            P[h][1] = pbv[2] | (pbv[3] << 16);
        }
    };

    // SWAR neighbor counts + gather + normalize + NT store for one output row.
    auto OUTROW = [&](int r, const unsigned (&T)[2][2], const unsigned (&M)[2][2],
                      const unsigned (&B)[2][2], const unsigned (&P)[2][2]) {
        unsigned C[2][2];
        #pragma unroll
        for (int h = 0; h < 2; h++) {
            C[h][0] = T[h][0] + M[h][0] + B[h][0];
            C[h][1] = T[h][1] + M[h][1] + B[h][1];
        }
        // cross-lane / cross-half colsum edges (cols 4L-1 and 4L+4 per half)
        unsigned upA = __shfl_up(C[0][1], 1) >> 16;   if (lane == 0)  upA = 0;          // col -1: image edge
        unsigned ebA = __shfl(C[0][1], 63) >> 16;                                        // col 255 -> halfB lane0
        unsigned upB = __shfl_up(C[1][1], 1) >> 16;   if (lane == 0)  upB = ebA;
        unsigned e0B = __shfl(C[1][0], 0) & 0xFFFFu;                                     // col 256 -> halfA lane63
        unsigned dnA = __shfl_down(C[0][0], 1) & 0xFFFFu; if (lane == 63) dnA = e0B;
        unsigned dnB = __shfl_down(C[1][0], 1) & 0xFFFFu; if (lane == 63) dnB = 0;       // col 512: image edge
        const unsigned up[2] = {upA, upB}, dn[2] = {dnA, dnB};

        float res[4][2][4];  // [class][half][px]
        #pragma unroll
        for (int h = 0; h < 2; h++) {
            // L(j)=C(j-1), R(j)=C(j+1) packed; note L-word1 == R-word0 (= c1|c2<<16)
            unsigned L0 = (C[h][0] << 16) | up[h];
            unsigned R0 = (C[h][0] >> 16) | (C[h][1] << 16);
            unsigned R1 = (C[h][1] >> 16) | (dn[h] << 16);
            unsigned PKw[2];
            PKw[0] = C[h][0] + L0 + R0 - M[h][0];   // nibble-wise 3x3 sum minus center, <= 8
            PKw[1] = C[h][1] + R0 + R1 - M[h][1];
            #pragma unroll
            for (int j = 0; j < 4; j++) {
                unsigned pk = (PKw[j >> 1]  >> (16 * (j & 1))) & 0xFFFFu;
                unsigned pb = (P[h][j >> 1] >> (16 * (j & 1))) & 0xFFFFu;
                float cs = 0.0f;
                float cal[4];
                #pragma unroll
                for (int c = 0; c < 4; c++) {
                    int cnt = (int)((pk >> (4 * c)) & 0xFu);   // [0,8]
                    int bin = (int)((pb >> (4 * c)) & 0xFu);   // [0,14]
                    float v = vf[c * 135 + cnt * 15 + bin];
                    cal[c] = v;
                    cs += v;                                   // ref class order
                }
                if (cs == 0.0f) cs = 1.0f;
                float inv = __builtin_amdgcn_rcpf(cs);         // tolerance 1.97e-2 >> 1 ULP
                #pragma unroll
                for (int c = 0; c < 4; c++) res[c][h][j] = cal[c] * inv;
            }
        }
        float* rp = ob + (r << 9);
        #pragma unroll
        for (int c = 0; c < 4; c++) {
            vfloat4 v0; v0.x = res[c][0][0]; v0.y = res[c][0][1]; v0.z = res[c][0][2]; v0.w = res[c][0][3];
            vfloat4 v1; v1.x = res[c][1][0]; v1.y = res[c][1][1]; v1.z = res[c][1][2]; v1.w = res[c][1][3];
            __builtin_nontemporal_store(v0, reinterpret_cast<vfloat4*>(rp + (size_t)c * HW + colA));
            __builtin_nontemporal_store(v1, reinterpret_cast<vfloat4*>(rp + (size_t)c * HW + colB));
        }
    };

    auto ROT = [&](unsigned (&T)[2][2], unsigned (&M)[2][2], const unsigned (&B)[2][2],
                   unsigned (&PC)[2][2], const unsigned (&PN)[2][2]) {
        #pragma unroll
        for (int h = 0; h < 2; h++)
            #pragma unroll
            for (int k = 0; k < 2; k++) {
                T[h][k] = M[h][k]; M[h][k] = B[h][k]; PC[h][k] = PN[h][k];
            }
    };

    vfloat4 U[4][2], V[4][2];
    unsigned T[2][2], M[2][2], B[2][2], PC[2][2], PN[2][2];

    // prologue: top halo + first interior row; vf ds_write overlaps the row loads
    LOADROW(U, (grp > 0) ? (h0 - 1) : 0);
    LOADROW(V, h0);
    #pragma unroll
    for (int i = 0; i < 9; i++) {
        int idx = 64 * i + lane;
        if (idx < 540) vf[idx] = vfr[i];
    }
    NIBROW(U, T);
    if (grp == 0) { T[0][0] = T[0][1] = T[1][0] = T[1][1] = 0; }
    LOADROW(U, h0 + 1);
    NIBPBROW(V, M, PC);
    LOADROW(V, h0 + 2);

    // it0: output row h0
    NIBPBROW(U, B, PN);
    LOADROW(U, h0 + 3);
    OUTROW(h0, T, M, B, PC);
    ROT(T, M, B, PC, PN);

    // it1: output row h0+1
    NIBPBROW(V, B, PN);
    LOADROW(V, (grp < 127) ? (h0 + 4) : 511);   // bottom halo (clamped; nib zeroed below)
    OUTROW(h0 + 1, T, M, B, PC);
    ROT(T, M, B, PC, PN);

    // it2: output row h0+2
    NIBPBROW(U, B, PN);
    OUTROW(h0 + 2, T, M, B, PC);
    ROT(T, M, B, PC, PN);

    // it3: output row h0+3 (bottom halo: argmax only)
    NIBROW(V, B);
    if (grp == 127) { B[0][0] = B[0][1] = B[1][0] = B[1][1] = 0; }
    OUTROW(h0 + 3, T, M, B, PC);
}

extern "C" void kernel_launch(void* const* d_in, const int* in_sizes, int n_in,
                              void* d_out, int out_size, void* d_ws, size_t ws_size,
                              hipStream_t stream) {
    const float* logits    = (const float*)d_in[0];
    const float* val_freqs = (const float*)d_in[1];
    float* out             = (float*)d_out;

    dim3 block(256, 1, 1);
    dim3 grid(512, 1, 1);   // 2048 wave-segments / 4 waves per block
    hipLaunchKernelGGL(nectar_binning_kernel, grid, block, 0, stream,
                       logits, val_freqs, out);
}